// Round 7
// baseline (232.679 us; speedup 1.0000x reference)
//
#include <hip/hip_runtime.h>
#include <hip/hip_bf16.h>

// ---------------------------------------------------------------------------
// ClassicalSelfAttention: B=4, S=2048, D=1024, fp32 in/out.
// R14: consolidation. R13's qkv merge was ~neutral in-kernel and -1.8us
// worse in total -> reverted to the R10 split (best measured, 230.4us).
// One zero-risk change: launch order prep -> qkv_v -> qkv_qk -> scores ->
// pv. scores depends only on dQ/dK; running qkv_qk LAST before scores
// leaves dQ/dK L2-hot at scores' launch (previously qkv_v's 16MB Vt stream
// sat between them, evicting dQ/dK; qkv_qk=40us vs scores=46.5us on the
// IDENTICAL loop/grid -- L2 state at launch is the main delta).
// Pipeline: prep; qkv_v (128^2, Vt transposed); qkv_qk (8-phase 256^2,
//   grid 256); scores (P=exp(qk/32-20) bf16 + partials); pv ((P@V)/sum).
// ---------------------------------------------------------------------------

using floatx4 = __attribute__((ext_vector_type(4))) float;
using shortx8 = __attribute__((ext_vector_type(8))) short;
using shortx4 = __attribute__((ext_vector_type(4))) short;

__device__ __forceinline__ short f2bf(float f) {
    __hip_bfloat16 h = __float2bfloat16(f);
    return *reinterpret_cast<short*>(&h);
}
__device__ __forceinline__ float bf2f(short s) {
    unsigned u = (unsigned)(unsigned short)s << 16;
    return __uint_as_float(u);
}

#define MFMA16(a, b, c) __builtin_amdgcn_mfma_f32_16x16x32_bf16((a), (b), (c), 0, 0, 0)

__device__ __forceinline__ void gld_lds16(const void* g, void* l) {
    __builtin_amdgcn_global_load_lds(
        (const __attribute__((address_space(1))) void*)g,
        (__attribute__((address_space(3))) void*)l, 16, 0, 0);
}

// ---------------------------------------------------------------------------
// Fragment readers (granule swizzle: LDS[r][g] holds global granule g^(r&7);
// write-side inverse-swizzle at the global source, read-side XOR).
// ---------------------------------------------------------------------------
template<int MH>
__device__ __forceinline__ void rdA(const short* sAb, int wm, int lrow,
                                    int xo0, int xo1, shortx8 (&af)[4][2]) {
    const short* base = sAb + ((wm << 7) + (MH << 6) + lrow) * 64;
#pragma unroll
    for (int i = 0; i < 4; ++i) {
        af[i][0] = *reinterpret_cast<const shortx8*>(base + i * 1024 + xo0);
        af[i][1] = *reinterpret_cast<const shortx8*>(base + i * 1024 + xo1);
    }
}
template<int NH>
__device__ __forceinline__ void rdB(const short* sBb, int wn, int lrow,
                                    int xo0, int xo1, shortx8 (&bf)[4][2]) {
    const short* base = sBb + ((wn << 6) + (NH << 5) + lrow) * 64;
#pragma unroll
    for (int j = 0; j < 2; ++j) {
        bf[NH * 2 + j][0] = *reinterpret_cast<const shortx8*>(base + j * 1024 + xo0);
        bf[NH * 2 + j][1] = *reinterpret_cast<const shortx8*>(base + j * 1024 + xo1);
    }
}
template<int MH, int NH>
__device__ __forceinline__ void mfq(shortx8 (&af)[4][2], shortx8 (&bf)[4][2],
                                    floatx4 (&acc)[8][4]) {
    __builtin_amdgcn_s_setprio(1);
#pragma unroll
    for (int i = 0; i < 4; ++i) {
#pragma unroll
        for (int j = 0; j < 2; ++j) {
            acc[MH * 4 + i][NH * 2 + j] =
                MFMA16(af[i][0], bf[NH * 2 + j][0], acc[MH * 4 + i][NH * 2 + j]);
            acc[MH * 4 + i][NH * 2 + j] =
                MFMA16(af[i][1], bf[NH * 2 + j][1], acc[MH * 4 + i][NH * 2 + j]);
        }
    }
    __builtin_amdgcn_s_setprio(0);
}

// C[256x256] += A[256xK] @ B[256xK]^T, 512 threads (8 waves, 2Mx4N).
// (R8, harness-verified; hazard audit in R8/R9 history.)
__device__ __forceinline__ void gemm256_loop8(
    const short* __restrict__ A, const short* __restrict__ B,
    int lda, int ldb, int K,
    short* sA, short* sB, floatx4 (&acc)[8][4], int t)
{
    const int w = t >> 6, l = t & 63;
    const int wm = w >> 2, wn = w & 3;
    const int lrow = l & 15, quad = l >> 4, r8 = lrow & 7;
    const int xo0 = (quad ^ r8) << 3;
    const int xo1 = ((quad + 4) ^ r8) << 3;
    const int rr = t >> 3;                       // 0..63
    const int gsw = ((t & 7) ^ (rr & 7)) << 3;   // inverse-swizzled src granule
    const short* gA0 = A + (size_t)rr * lda + gsw;
    const short* gA1 = A + (size_t)(128 + rr) * lda + gsw;
    const short* gB0 = B + (size_t)rr * ldb + gsw;
    const short* gB1 = B + (size_t)(128 + rr) * ldb + gsw;
    const int wofs = w << 9;                     // wave-uniform LDS base

    auto stage = [&](const short* g, int ld, int kt, short* ldsb) {
        const short* p = g + kt;
        gld_lds16(p, ldsb + wofs);                       // rows base+0..63
        gld_lds16(p + (size_t)(ld << 6), ldsb + wofs + 4096); // rows +64..127
    };

    shortx8 af[4][2], bf[4][2];
    const int NT = K >> 6;

    stage(gA0, lda, 0, sA);
    stage(gA1, lda, 0, sA + 8192);
    stage(gB0, ldb, 0, sB);
    stage(gB1, ldb, 0, sB + 8192);
    stage(gB0, ldb, 64, sB + 16384);
    stage(gB1, ldb, 64, sB + 16384 + 8192);
    asm volatile("s_waitcnt vmcnt(4)" ::: "memory");   // T0's 8 landed
    __builtin_amdgcn_s_barrier();

    for (int T = 0; T < NT; T += 2) {
        const bool more = (T + 2) < NT;
        const int ktA1 = (T + 1) << 6;
        const int ktN2 = (T + 2) << 6;
        const int ktB3 = (T + 3) << 6;
        short* sA0 = sA;           short* sB0 = sB;
        short* sA1 = sA + 16384;   short* sB1 = sB + 16384;

        // ---------------- tile T (buf0) ----------------
        rdA<0>(sA0, wm, lrow, xo0, xo1, af);
        rdB<0>(sB0, wn, lrow, xo0, xo1, bf);
        stage(gA0, lda, ktA1, sA1);
        asm volatile("s_waitcnt lgkmcnt(8)" ::: "memory");
        __builtin_amdgcn_s_barrier();
        asm volatile("s_waitcnt lgkmcnt(0)" ::: "memory");
        __builtin_amdgcn_sched_barrier(0);
        mfq<0, 0>(af, bf, acc);
        __builtin_amdgcn_s_barrier();

        rdB<1>(sB0, wn, lrow, xo0, xo1, bf);
        stage(gA1, lda, ktA1, sA1 + 8192);
        __builtin_amdgcn_s_barrier();
        asm volatile("s_waitcnt lgkmcnt(0)" ::: "memory");
        __builtin_amdgcn_sched_barrier(0);
        mfq<0, 1>(af, bf, acc);
        __builtin_amdgcn_s_barrier();

        rdA<1>(sA0, wm, lrow, xo0, xo1, af);
        if (more) stage(gB0, ldb, ktN2, sB0);
        __builtin_amdgcn_s_barrier();
        asm volatile("s_waitcnt lgkmcnt(0)" ::: "memory");
        __builtin_amdgcn_sched_barrier(0);
        mfq<1, 0>(af, bf, acc);
        __builtin_amdgcn_s_barrier();

        if (more) stage(gB1, ldb, ktN2, sB0 + 8192);
        __builtin_amdgcn_s_barrier();
        __builtin_amdgcn_sched_barrier(0);
        mfq<1, 1>(af, bf, acc);
        if (more) { asm volatile("s_waitcnt vmcnt(4)" ::: "memory"); }
        else      { asm volatile("s_waitcnt vmcnt(0)" ::: "memory"); }
        __builtin_amdgcn_s_barrier();

        // ---------------- tile T+1 (buf1) ----------------
        rdA<0>(sA1, wm, lrow, xo0, xo1, af);
        rdB<0>(sB1, wn, lrow, xo0, xo1, bf);
        if (more) stage(gA0, lda, ktN2, sA0);
        asm volatile("s_waitcnt lgkmcnt(8)" ::: "memory");
        __builtin_amdgcn_s_barrier();
        asm volatile("s_waitcnt lgkmcnt(0)" ::: "memory");
        __builtin_amdgcn_sched_barrier(0);
        mfq<0, 0>(af, bf, acc);
        __builtin_amdgcn_s_barrier();

        rdB<1>(sB1, wn, lrow, xo0, xo1, bf);
        if (more) stage(gA1, lda, ktN2, sA0 + 8192);
        __builtin_amdgcn_s_barrier();
        asm volatile("s_waitcnt lgkmcnt(0)" ::: "memory");
        __builtin_amdgcn_sched_barrier(0);
        mfq<0, 1>(af, bf, acc);
        __builtin_amdgcn_s_barrier();

        rdA<1>(sA1, wm, lrow, xo0, xo1, af);
        if (more) stage(gB0, ldb, ktB3, sB1);
        __builtin_amdgcn_s_barrier();
        asm volatile("s_waitcnt lgkmcnt(0)" ::: "memory");
        __builtin_amdgcn_sched_barrier(0);
        mfq<1, 0>(af, bf, acc);
        __builtin_amdgcn_s_barrier();

        if (more) stage(gB1, ldb, ktB3, sB1 + 8192);
        __builtin_amdgcn_s_barrier();
        __builtin_amdgcn_sched_barrier(0);
        mfq<1, 1>(af, bf, acc);
        if (more) { asm volatile("s_waitcnt vmcnt(4)" ::: "memory"); }
        __builtin_amdgcn_s_barrier();
    }
}

// ---------------------------------------------------------------------------
// 128x128 2-phase mainloop (R3/R4, measured 0 conflicts): used by qkv_v + pv.
// ---------------------------------------------------------------------------
__device__ __forceinline__ void gemm_loop(
    const short* __restrict__ A, const short* __restrict__ B,
    size_t lda, size_t ldb, int K,
    short* as_, short* bs_, floatx4 (&acc)[4][4], int w, int l)
{
    const int lr8 = l >> 3;
    const int swz = ((l & 7) ^ lr8) * 8;
    const int lrow = l & 15, quad = l >> 4;
    const int wr = w >> 1, wc = w & 1;
    const int r8r = lrow & 7;
    const short* pa = A + (size_t)(w * 32 + lr8) * lda + swz;
    const short* pb = B + (size_t)(w * 32 + lr8) * ldb + swz;
    short* la = as_ + w * 4 * 512;
    short* lb = bs_ + w * 4 * 512;

    for (int kt = 0; kt < K; kt += 64) {
        for (int c = 0; c < 4; ++c) {
            gld_lds16(pa + (size_t)c * 8 * lda + kt, la + c * 512);
            gld_lds16(pb + (size_t)c * 8 * ldb + kt, lb + c * 512);
        }
        __syncthreads();
        for (int kk = 0; kk < 64; kk += 32) {
            const int xoff = (((kk >> 3) + quad) ^ r8r) << 3;
            shortx8 af[4], bfr[4];
            for (int i = 0; i < 4; ++i)
                af[i] = *reinterpret_cast<const shortx8*>(
                    &as_[(size_t)(wr * 64 + i * 16 + lrow) * 64 + xoff]);
            for (int j = 0; j < 4; ++j)
                bfr[j] = *reinterpret_cast<const shortx8*>(
                    &bs_[(size_t)(wc * 64 + j * 16 + lrow) * 64 + xoff]);
            for (int i = 0; i < 4; ++i)
                for (int j = 0; j < 4; ++j)
                    acc[i][j] = MFMA16(af[i], bfr[j], acc[i][j]);
        }
        __syncthreads();
    }
}

// --------------------------------------------------------------------------
// prep: id<4096 xconv; id<4864 wconv 64x64 tile; id<4867 bias concat.
// --------------------------------------------------------------------------
__global__ __launch_bounds__(256) void prep_kernel(
    const float* __restrict__ X,
    const float* __restrict__ Wq, const float* __restrict__ Wk,
    const float* __restrict__ Wv,
    const float* __restrict__ bq, const float* __restrict__ bk,
    const float* __restrict__ bv,
    short* __restrict__ Xb, short* __restrict__ Wt,
    float* __restrict__ bcat)
{
    const int id = blockIdx.x, t = threadIdx.x;
    if (id < 4096) {
        size_t i = ((size_t)id * 256 + t) * 8;
        float4 v0 = *reinterpret_cast<const float4*>(X + i);
        float4 v1 = *reinterpret_cast<const float4*>(X + i + 4);
        shortx8 s;
        s[0] = f2bf(v0.x); s[1] = f2bf(v0.y); s[2] = f2bf(v0.z); s[3] = f2bf(v0.w);
        s[4] = f2bf(v1.x); s[5] = f2bf(v1.y); s[6] = f2bf(v1.z); s[7] = f2bf(v1.w);
        *reinterpret_cast<shortx8*>(Xb + i) = s;
    } else if (id < 4864) {
        __shared__ float tl[64][65];
        const int wid = id - 4096;
        const int z = wid >> 8, t16 = wid & 255;
        const float* src = (z == 0) ? Wq : (z == 1) ? Wk : Wv;
        short* dst = Wt + (size_t)z * 1024 * 1024;
        const int k0 = (t16 >> 4) * 64, n0 = (t16 & 15) * 64;
        for (int i = t; i < 64 * 64; i += 256) {
            int r = i >> 6, c = i & 63;
            tl[r][c] = src[(size_t)(k0 + r) * 1024 + n0 + c];
        }
        __syncthreads();
        for (int i = t; i < 64 * 64; i += 256) {
            int r = i >> 6, c = i & 63;
            dst[(size_t)(n0 + r) * 1024 + k0 + c] = f2bf(tl[c][r]);
        }
    } else {
        const int z = id - 4864;
        const float* bsrc = (z == 0) ? bq : (z == 1) ? bk : bv;
        for (int i = t; i < 1024; i += 256) bcat[z * 1024 + i] = bsrc[i];
    }
}

// --------------------------------------------------------------------------
// V part of QKV: Vt[b][1024(d)][2048(s)] = (Xb @ Wt[2048:3072]^T + bias)^T.
// 128^2 2-phase loop, grid (64, 8) = 512 blocks. Launched FIRST of the two
// qkv kernels so its Vt stream doesn't sit between qkv_qk and scores.
// --------------------------------------------------------------------------
__global__ __launch_bounds__(256) void qkv_v_kernel(
    const short* __restrict__ Xb, const short* __restrict__ Wt,
    const float* __restrict__ bcat, short* __restrict__ Vt)
{
    __shared__ short as_[128 * 64];
    __shared__ short bs_[128 * 64];
    const int t = threadIdx.x, w = t >> 6, l = t & 63;
    const int m0 = blockIdx.x * 128;
    const int n0 = 2048 + blockIdx.y * 128;
    const int wr = w >> 1, wc = w & 1, lrow = l & 15, quad = l >> 4;

    floatx4 acc[4][4];
    for (int i = 0; i < 4; ++i)
        for (int j = 0; j < 4; ++j) acc[i][j] = floatx4{0.f, 0.f, 0.f, 0.f};

    gemm_loop(Xb + (size_t)m0 * 1024, Wt + (size_t)n0 * 1024,
              1024, 1024, 1024, as_, bs_, acc, w, l);

    for (int i = 0; i < 4; ++i) {
        int rbase = m0 + wr * 64 + i * 16 + quad * 4;
        int b = rbase >> 11, sl = rbase & 2047;
        for (int j = 0; j < 4; ++j) {
            int coln = n0 + wc * 64 + j * 16 + lrow;   // 2048..3071
            int col = coln & 1023;
            float bvv = bcat[coln];
            shortx4 s;
            for (int r = 0; r < 4; ++r) s[r] = f2bf(acc[i][j][r] + bvv);
            *reinterpret_cast<shortx4*>(
                &Vt[((size_t)b * 1024 + col) * 2048 + sl]) = s;
        }
    }
}

// --------------------------------------------------------------------------
// QK part of QKV: C[8192][2048] = Xb @ Wt[0:2048]^T + bcat.  sec = n0>>10:
//   0 -> dQ bf16 [8192][1024], 1 -> dK.
// Grid (32, 8) = exactly 256 blocks (1 block/CU, single dispatch round).
// Launched immediately before scores: dQ/dK L2-hot at scores' start.
// --------------------------------------------------------------------------
__global__ __launch_bounds__(512, 2) void qkv_qk_kernel(
    const short* __restrict__ Xb, const short* __restrict__ Wt,
    const float* __restrict__ bcat, short* __restrict__ dQ,
    short* __restrict__ dK)
{
    __shared__ short sA[2 * 16384];
    __shared__ short sB[2 * 16384];
    const int t = threadIdx.x;
    const int m0 = blockIdx.x * 256, n0 = blockIdx.y * 256;
    const int w = t >> 6, l = t & 63;
    const int wm = w >> 2, wn = w & 3, lrow = l & 15, quad = l >> 4;
    const int sec = n0 >> 10;

    floatx4 acc[8][4];
#pragma unroll
    for (int i = 0; i < 8; ++i)
#pragma unroll
        for (int j = 0; j < 4; ++j) acc[i][j] = floatx4{0.f, 0.f, 0.f, 0.f};

    gemm256_loop8(Xb + (size_t)m0 * 1024, Wt + (size_t)n0 * 1024,
                  1024, 1024, 1024, sA, sB, acc, t);

    short* outN = (sec == 0) ? dQ : dK;
#pragma unroll
    for (int i = 0; i < 8; ++i) {
        int rbase = m0 + wm * 128 + i * 16 + quad * 4;
#pragma unroll
        for (int j = 0; j < 4; ++j) {
            int coln = n0 + wn * 64 + j * 16 + lrow;   // 0..2047
            int col = coln & 1023;
            float bvv = bcat[coln];
#pragma unroll
            for (int r = 0; r < 4; ++r)
                outN[(size_t)(rbase + r) * 1024 + col] =
                    f2bf(acc[i][j][r] + bvv);
        }
    }
}

// --------------------------------------------------------------------------
// P[m][key] = exp(q.k/32 - 20) bf16 (unnormalized); per-(row, key-tile)
// partial sums -> partials[row*8 + ytile] (no atomics: wn-waves combine via
// disjoint LDS [256][4] slots reusing sA after the final mainloop barrier).
// Grid (rows/256, 8). Full-chunk (gridDim.x==32): bijective XCD remap --
// id%8 (the XCD) fixes the batch (c>>1): per-XCD dK 4MB + dQ 2MB.
// --------------------------------------------------------------------------
__global__ __launch_bounds__(512, 2) void scores_kernel(
    const short* __restrict__ dQ, const short* __restrict__ dK,
    short* __restrict__ P, float* __restrict__ partials, int row_start)
{
    __shared__ short sA[2 * 16384];
    __shared__ short sB[2 * 16384];
    const int t = threadIdx.x;
    int bx = blockIdx.x, by = blockIdx.y;
    if (gridDim.x == 32) {
        const int c = bx & 7;
        const int k = (bx >> 3) + (by << 2);      // 0..31
        const int bb = c >> 1, half = c & 1;
        bx = bb * 8 + (k & 3) + 4 * half;          // row-tile 0..31
        by = k >> 2;                               // key-tile 0..7
    }
    const int m0 = bx * 256;                  // chunk-local q rows
    const int n0 = by * 256;                  // key tile
    const int g0 = row_start + m0;
    const int b = g0 >> 11;
    const int w = t >> 6, l = t & 63;
    const int wm = w >> 2, wn = w & 3, lrow = l & 15, quad = l >> 4;

    floatx4 acc[8][4];
#pragma unroll
    for (int i = 0; i < 8; ++i)
#pragma unroll
        for (int j = 0; j < 4; ++j) acc[i][j] = floatx4{0.f, 0.f, 0.f, 0.f};

    gemm256_loop8(dQ + (size_t)g0 * 1024, dK + ((size_t)b * 2048 + n0) * 1024,
                  1024, 1024, 1024, sA, sB, acc, t);

    // sred[row_local][wn]: each (row, wn) written exactly once -> no atomics.
    float* sred = reinterpret_cast<float*>(sA);   // 256*4 floats = 4 KiB
#pragma unroll
    for (int i = 0; i < 8; ++i) {
        int rl = wm * 128 + i * 16 + quad * 4;    // block-local row base
        int rloc = m0 + rl;
        float rs[4] = {0.f, 0.f, 0.f, 0.f};
#pragma unroll
        for (int j = 0; j < 4; ++j) {
            int col = n0 + wn * 64 + j * 16 + lrow;
#pragma unroll
            for (int r = 0; r < 4; ++r) {
                short pb = f2bf(__expf(acc[i][j][r] * 0.03125f - 20.0f));
                P[(size_t)(rloc + r) * 2048 + col] = pb;
                rs[r] += bf2f(pb);
            }
        }
#pragma unroll
        for (int r = 0; r < 4; ++r)
            for (int m = 1; m <= 8; m <<= 1)
                rs[r] += __shfl_xor(rs[r], m, 64);
        if (lrow == 0)
#pragma unroll
            for (int r = 0; r < 4; ++r)
                sred[(rl + r) * 4 + wn] = rs[r];
    }
    __syncthreads();
    if (t < 256) {
        float s = sred[t * 4] + sred[t * 4 + 1] + sred[t * 4 + 2] + sred[t * 4 + 3];
        partials[(size_t)(row_start + m0 + t) * 8 + by] = s;
    }
}

// --------------------------------------------------------------------------
// Out[row][d] = (P[m][:] @ V[b][:,d]) / sum_y partials[row][y].
// Vt bf16 [b][d][key]. 128^2 2-phase loop (proven 44.3us), grid (rows/128,
// 8). Full-chunk (gridDim.x==64): bijective XCD remap -- each XCD
// batch-local: Vt working set 16MB -> 4MB.
// --------------------------------------------------------------------------
__global__ __launch_bounds__(256) void pv_kernel(
    const short* __restrict__ P, const short* __restrict__ Vt,
    const float* __restrict__ partials, float* __restrict__ Out, int row_start)
{
    __shared__ short as_[128 * 64];
    __shared__ short bs_[128 * 64];
    const int t = threadIdx.x, w = t >> 6, l = t & 63;
    int bx = blockIdx.x, by = blockIdx.y;
    if (gridDim.x == 64) {
        const int c = bx & 7;
        const int k = (bx >> 3) + (by << 3);      // 0..63
        const int bb = c >> 1, half = c & 1;
        bx = bb * 16 + (k & 7) + 8 * half;         // row-tile 0..63
        by = k >> 3;                               // d-tile 0..7
    }
    const int m0 = bx * 128;                  // chunk-local rows
    const int n0 = by * 128;                  // d tile
    const int g0 = row_start + m0;
    const int b = g0 >> 11;
    const int wr = w >> 1, wc = w & 1, lrow = l & 15, quad = l >> 4;

    floatx4 acc[4][4];
    for (int i = 0; i < 4; ++i)
        for (int j = 0; j < 4; ++j) acc[i][j] = floatx4{0.f, 0.f, 0.f, 0.f};

    gemm_loop(P + (size_t)m0 * 2048, Vt + ((size_t)b * 1024 + n0) * 2048,
              2048, 2048, 2048, as_, bs_, acc, w, l);

    for (int i = 0; i < 4; ++i) {
        int rloc = m0 + wr * 64 + i * 16 + quad * 4;
        int rglb = row_start + rloc;
        float is[4];
        for (int r = 0; r < 4; ++r) {
            const float4* pp =
                reinterpret_cast<const float4*>(&partials[(size_t)(rglb + r) * 8]);
            float4 p0 = pp[0], p1 = pp[1];
            float s = (p0.x + p0.y) + (p0.z + p0.w) +
                      (p1.x + p1.y) + (p1.z + p1.w);
            is[r] = 1.0f / s;
        }
        for (int j = 0; j < 4; ++j) {
            int col = n0 + wc * 64 + j * 16 + lrow;
            for (int r = 0; r < 4; ++r)
                Out[(size_t)(rglb + r) * 1024 + col] = acc[i][j][r] * is[r];
        }
    }
}

// --------------------------------------------------------------------------
extern "C" void kernel_launch(void* const* d_in, const int* in_sizes, int n_in,
                              void* d_out, int out_size, void* d_ws, size_t ws_size,
                              hipStream_t stream)
{
    const float* x  = (const float*)d_in[0];
    const float* Wq = (const float*)d_in[1];
    const float* bq = (const float*)d_in[2];
    const float* Wk = (const float*)d_in[3];
    const float* bk = (const float*)d_in[4];
    const float* Wv = (const float*)d_in[5];
    const float* bv = (const float*)d_in[6];
    float* out = (float*)d_out;

    // d_out doubles as Q/K scratch (exactly 32 MiB): safe by stream ordering.
    short* dQ = (short*)d_out;
    short* dK = dQ + (size_t)8192 * 1024;

    char* ws = (char*)d_ws;
    short* Wt   = (short*)ws;                                 // 6 MiB
    float* bcat = (float*)(ws + 6291456);                     // 12 KiB
    float* partials = (float*)(ws + 6291456 + 12288);         // 256 KiB [8192][8]
    short* Vt   = (short*)(ws + 6291456 + 12288 + 262144);    // 16 MiB
    char*  region = ws + 6291456 + 12288 + 262144 + 16777216; // P / Xb
    const size_t base = 6291456 + 12288 + 262144 + 16777216;  // ~22.3 MiB

    size_t avail = ws_size > base ? ws_size - base : 0;
    long rows_fit = (long)(avail / 4096);   // P row = 2048 bf16 = 4 KiB
    int chunk = (int)(rows_fit & ~255L);    // scores tiles are 256 rows
    if (chunk > 8192) chunk = 8192;
    if (chunk < 256) chunk = 256;           // needs ws >= ~23.3 MiB
    short* Xb = (short*)region;             // 16 MiB, dead before P is written
    short* P  = (short*)region;

    prep_kernel<<<dim3(4867), 256, 0, stream>>>(x, Wq, Wk, Wv, bq, bk, bv,
                                                Xb, Wt, bcat);
    // V first, QK last: dQ/dK are the freshest L2 lines when scores starts.
    qkv_v_kernel<<<dim3(64, 8), 256, 0, stream>>>(Xb, Wt, bcat, Vt);
    qkv_qk_kernel<<<dim3(32, 8), 512, 0, stream>>>(Xb, Wt, bcat, dQ, dK);

    for (int rs = 0; rs < 8192; rs += chunk) {
        int rows = 8192 - rs;
        if (rows > chunk) rows = chunk;
        scores_kernel<<<dim3(rows / 256, 8), 512, 0, stream>>>(dQ, dK, P, partials, rs);
        pv_kernel<<<dim3(rows / 128, 8), 256, 0, stream>>>(P, Vt, partials, out, rs);
    }
}

// Round 8
// 229.297 us; speedup vs baseline: 1.0147x; 1.0147x over previous
//
#include <hip/hip_runtime.h>
#include <hip/hip_bf16.h>

// ---------------------------------------------------------------------------
// ClassicalSelfAttention: B=4, S=2048, D=1024, fp32 in/out.
// R15: phase-amortization round. Measured per-phase cost of the 8-phase
// 256^2 loop = ~1520 cy vs ~160 cy of MFMA content -> ~90% is fixed
// lockstep overhead (barriers + ds latency + drain) paid PER PHASE.
// New gemm256_loop4: same 256^2 tile, same data movement (24 ds_reads +
// 8 staged loads per K-tile), same 64 MFMA/K-tile, but 2 phases/K-tile
// (32 MFMA/phase) instead of 4 -> half the barriers. B-frags already
// persist across the A-half pair, so no extra registers (af+bf = 64 VGPR,
// as in R8). Applied to qkv_qk + scores. pv/qkv_v unchanged (128^2 loop).
// NOT R12's failed variant: that shrank the tile (16 MFMA/phase); this
// keeps 256^2 and doubles MFMA/phase.
// Pipeline: prep; qkv_v; qkv_qk; scores (P=exp(qk/32-20) bf16 + partials);
//   pv ((P@V)/sum).
// ---------------------------------------------------------------------------

using floatx4 = __attribute__((ext_vector_type(4))) float;
using shortx8 = __attribute__((ext_vector_type(8))) short;
using shortx4 = __attribute__((ext_vector_type(4))) short;

__device__ __forceinline__ short f2bf(float f) {
    __hip_bfloat16 h = __float2bfloat16(f);
    return *reinterpret_cast<short*>(&h);
}
__device__ __forceinline__ float bf2f(short s) {
    unsigned u = (unsigned)(unsigned short)s << 16;
    return __uint_as_float(u);
}

#define MFMA16(a, b, c) __builtin_amdgcn_mfma_f32_16x16x32_bf16((a), (b), (c), 0, 0, 0)

__device__ __forceinline__ void gld_lds16(const void* g, void* l) {
    __builtin_amdgcn_global_load_lds(
        (const __attribute__((address_space(1))) void*)g,
        (__attribute__((address_space(3))) void*)l, 16, 0, 0);
}

// ---------------------------------------------------------------------------
// Fragment readers (granule swizzle: LDS[r][g] holds global granule g^(r&7);
// write-side inverse-swizzle at the global source, read-side XOR).
// ---------------------------------------------------------------------------
template<int MH>
__device__ __forceinline__ void rdA(const short* sAb, int wm, int lrow,
                                    int xo0, int xo1, shortx8 (&af)[4][2]) {
    const short* base = sAb + ((wm << 7) + (MH << 6) + lrow) * 64;
#pragma unroll
    for (int i = 0; i < 4; ++i) {
        af[i][0] = *reinterpret_cast<const shortx8*>(base + i * 1024 + xo0);
        af[i][1] = *reinterpret_cast<const shortx8*>(base + i * 1024 + xo1);
    }
}
template<int NH>
__device__ __forceinline__ void rdB(const short* sBb, int wn, int lrow,
                                    int xo0, int xo1, shortx8 (&bf)[4][2]) {
    const short* base = sBb + ((wn << 6) + (NH << 5) + lrow) * 64;
#pragma unroll
    for (int j = 0; j < 2; ++j) {
        bf[NH * 2 + j][0] = *reinterpret_cast<const shortx8*>(base + j * 1024 + xo0);
        bf[NH * 2 + j][1] = *reinterpret_cast<const shortx8*>(base + j * 1024 + xo1);
    }
}
template<int MH, int NH>
__device__ __forceinline__ void mfq(shortx8 (&af)[4][2], shortx8 (&bf)[4][2],
                                    floatx4 (&acc)[8][4]) {
    __builtin_amdgcn_s_setprio(1);
#pragma unroll
    for (int i = 0; i < 4; ++i) {
#pragma unroll
        for (int j = 0; j < 2; ++j) {
            acc[MH * 4 + i][NH * 2 + j] =
                MFMA16(af[i][0], bf[NH * 2 + j][0], acc[MH * 4 + i][NH * 2 + j]);
            acc[MH * 4 + i][NH * 2 + j] =
                MFMA16(af[i][1], bf[NH * 2 + j][1], acc[MH * 4 + i][NH * 2 + j]);
        }
    }
    __builtin_amdgcn_s_setprio(0);
}

// ---------------------------------------------------------------------------
// R15: C[256x256] += A[256xK] @ B[256xK]^T, 512 threads, 2 phases/K-tile.
// ph1: rd buf0.A-mh0 + ALL buf0.B (16 ds_reads) -> 32 MFMA (mh0 x nh0,nh1)
// ph2: rd buf0.A-mh1 (8 reads)                  -> 32 MFMA (mh1 x nh0,nh1)
// ph3/ph4: same on buf1.  Double-buffered; 2 K-tiles/iteration.
// Staging (region free = last read drained a barrier earlier):
//   ph1: A1(T+1)->buf1.mh1   [buf1.mh1 last read prev-ph4]
//   ph2: A0(T+2)->buf0.mh0, B(T+2)->buf0.B  [read ph1]
//   ph3: A1(T+2)->buf0.mh1   [read ph2]
//   ph4: A0(T+3)->buf1.mh0, B(T+3)->buf1.B  [read ph3]
// Gates (steady state; 2 loads per A-half stage, 4 per B pair):
//   ph2-end vmcnt(8): drains prev-ph4's 6 => T+1 A0+B landed for ph3 reads.
//   ph3-end vmcnt(8): drains ph1's 2      => T+1 A1 landed for ph4 reads.
//   ph4-end vmcnt(6): drains ph2's 6+ph3's 2 => T+2 landed for next ph1.
// Tail (more=false): ph2-end vmcnt(2), ph3-end vmcnt(0), ph4 no gate.
// Prologue: T0 full->buf0 (8), T1 A0+B->buf1 (6), vmcnt(6) => T0 landed.
// ---------------------------------------------------------------------------
__device__ __forceinline__ void gemm256_loop4(
    const short* __restrict__ A, const short* __restrict__ B,
    int lda, int ldb, int K,
    short* sA, short* sB, floatx4 (&acc)[8][4], int t)
{
    const int w = t >> 6, l = t & 63;
    const int wm = w >> 2, wn = w & 3;
    const int lrow = l & 15, quad = l >> 4, r8 = lrow & 7;
    const int xo0 = (quad ^ r8) << 3;
    const int xo1 = ((quad + 4) ^ r8) << 3;
    const int rr = t >> 3;                       // 0..63
    const int gsw = ((t & 7) ^ (rr & 7)) << 3;   // inverse-swizzled src granule
    const short* gA0 = A + (size_t)rr * lda + gsw;
    const short* gA1 = A + (size_t)(128 + rr) * lda + gsw;
    const short* gB0 = B + (size_t)rr * ldb + gsw;
    const short* gB1 = B + (size_t)(128 + rr) * ldb + gsw;
    const int wofs = w << 9;                     // wave-uniform LDS base

    auto stage = [&](const short* g, int ld, int kt, short* ldsb) {
        const short* p = g + kt;
        gld_lds16(p, ldsb + wofs);                       // rows base+0..63
        gld_lds16(p + (size_t)(ld << 6), ldsb + wofs + 4096); // rows +64..127
    };

    shortx8 af[4][2], bf[4][2];
    const int NT = K >> 6;
    short* sA0 = sA;           short* sB0 = sB;
    short* sA1 = sA + 16384;   short* sB1 = sB + 16384;

    // prologue: T0 full -> buf0 [8]; T1 A-mh0 + B -> buf1 [6].
    stage(gA0, lda, 0, sA0); stage(gA1, lda, 0, sA0 + 8192);
    stage(gB0, ldb, 0, sB0); stage(gB1, ldb, 0, sB0 + 8192);
    stage(gA0, lda, 64, sA1);
    stage(gB0, ldb, 64, sB1); stage(gB1, ldb, 64, sB1 + 8192);
    asm volatile("s_waitcnt vmcnt(6)" ::: "memory");   // T0's 8 landed
    __builtin_amdgcn_s_barrier();

    for (int T = 0; T < NT; T += 2) {
        const bool more = (T + 2) < NT;
        const int ktA1 = (T + 1) << 6;
        const int kt2  = (T + 2) << 6;
        const int kt3  = (T + 3) << 6;

        // ph1: tile T mh0 + all B; stage A1(T+1)->buf1.mh1
        rdA<0>(sA0, wm, lrow, xo0, xo1, af);
        rdB<0>(sB0, wn, lrow, xo0, xo1, bf);
        rdB<1>(sB0, wn, lrow, xo0, xo1, bf);
        stage(gA1, lda, ktA1, sA1 + 8192);
        asm volatile("s_waitcnt lgkmcnt(8)" ::: "memory");
        __builtin_amdgcn_s_barrier();
        asm volatile("s_waitcnt lgkmcnt(0)" ::: "memory");
        __builtin_amdgcn_sched_barrier(0);
        mfq<0, 0>(af, bf, acc);
        mfq<0, 1>(af, bf, acc);
        __builtin_amdgcn_s_barrier();

        // ph2: tile T mh1; stage A0(T+2)->buf0.mh0, B(T+2)->buf0.B
        rdA<1>(sA0, wm, lrow, xo0, xo1, af);
        if (more) {
            stage(gA0, lda, kt2, sA0);
            stage(gB0, ldb, kt2, sB0); stage(gB1, ldb, kt2, sB0 + 8192);
        }
        __builtin_amdgcn_s_barrier();
        asm volatile("s_waitcnt lgkmcnt(0)" ::: "memory");
        __builtin_amdgcn_sched_barrier(0);
        mfq<1, 0>(af, bf, acc);
        mfq<1, 1>(af, bf, acc);
        if (more) { asm volatile("s_waitcnt vmcnt(8)" ::: "memory"); }
        else      { asm volatile("s_waitcnt vmcnt(2)" ::: "memory"); }
        __builtin_amdgcn_s_barrier();

        // ph3: tile T+1 mh0 + all B; stage A1(T+2)->buf0.mh1
        rdA<0>(sA1, wm, lrow, xo0, xo1, af);
        rdB<0>(sB1, wn, lrow, xo0, xo1, bf);
        rdB<1>(sB1, wn, lrow, xo0, xo1, bf);
        if (more) stage(gA1, lda, kt2, sA0 + 8192);
        asm volatile("s_waitcnt lgkmcnt(8)" ::: "memory");
        __builtin_amdgcn_s_barrier();
        asm volatile("s_waitcnt lgkmcnt(0)" ::: "memory");
        __builtin_amdgcn_sched_barrier(0);
        mfq<0, 0>(af, bf, acc);
        mfq<0, 1>(af, bf, acc);
        if (more) { asm volatile("s_waitcnt vmcnt(8)" ::: "memory"); }
        else      { asm volatile("s_waitcnt vmcnt(0)" ::: "memory"); }
        __builtin_amdgcn_s_barrier();

        // ph4: tile T+1 mh1; stage A0(T+3)->buf1.mh0, B(T+3)->buf1.B
        rdA<1>(sA1, wm, lrow, xo0, xo1, af);
        if (more) {
            stage(gA0, lda, kt3, sA1);
            stage(gB0, ldb, kt3, sB1); stage(gB1, ldb, kt3, sB1 + 8192);
        }
        __builtin_amdgcn_s_barrier();
        asm volatile("s_waitcnt lgkmcnt(0)" ::: "memory");
        __builtin_amdgcn_sched_barrier(0);
        mfq<1, 0>(af, bf, acc);
        mfq<1, 1>(af, bf, acc);
        if (more) { asm volatile("s_waitcnt vmcnt(6)" ::: "memory"); }
        __builtin_amdgcn_s_barrier();
    }
}

// ---------------------------------------------------------------------------
// 128x128 2-phase mainloop (R3/R4, measured 0 conflicts): used by qkv_v + pv.
// ---------------------------------------------------------------------------
__device__ __forceinline__ void gemm_loop(
    const short* __restrict__ A, const short* __restrict__ B,
    size_t lda, size_t ldb, int K,
    short* as_, short* bs_, floatx4 (&acc)[4][4], int w, int l)
{
    const int lr8 = l >> 3;
    const int swz = ((l & 7) ^ lr8) * 8;
    const int lrow = l & 15, quad = l >> 4;
    const int wr = w >> 1, wc = w & 1;
    const int r8r = lrow & 7;
    const short* pa = A + (size_t)(w * 32 + lr8) * lda + swz;
    const short* pb = B + (size_t)(w * 32 + lr8) * ldb + swz;
    short* la = as_ + w * 4 * 512;
    short* lb = bs_ + w * 4 * 512;

    for (int kt = 0; kt < K; kt += 64) {
        for (int c = 0; c < 4; ++c) {
            gld_lds16(pa + (size_t)c * 8 * lda + kt, la + c * 512);
            gld_lds16(pb + (size_t)c * 8 * ldb + kt, lb + c * 512);
        }
        __syncthreads();
        for (int kk = 0; kk < 64; kk += 32) {
            const int xoff = (((kk >> 3) + quad) ^ r8r) << 3;
            shortx8 af[4], bfr[4];
            for (int i = 0; i < 4; ++i)
                af[i] = *reinterpret_cast<const shortx8*>(
                    &as_[(size_t)(wr * 64 + i * 16 + lrow) * 64 + xoff]);
            for (int j = 0; j < 4; ++j)
                bfr[j] = *reinterpret_cast<const shortx8*>(
                    &bs_[(size_t)(wc * 64 + j * 16 + lrow) * 64 + xoff]);
            for (int i = 0; i < 4; ++i)
                for (int j = 0; j < 4; ++j)
                    acc[i][j] = MFMA16(af[i], bfr[j], acc[i][j]);
        }
        __syncthreads();
    }
}

// --------------------------------------------------------------------------
// prep: id<4096 xconv; id<4864 wconv 64x64 tile; id<4867 bias concat.
// --------------------------------------------------------------------------
__global__ __launch_bounds__(256) void prep_kernel(
    const float* __restrict__ X,
    const float* __restrict__ Wq, const float* __restrict__ Wk,
    const float* __restrict__ Wv,
    const float* __restrict__ bq, const float* __restrict__ bk,
    const float* __restrict__ bv,
    short* __restrict__ Xb, short* __restrict__ Wt,
    float* __restrict__ bcat)
{
    const int id = blockIdx.x, t = threadIdx.x;
    if (id < 4096) {
        size_t i = ((size_t)id * 256 + t) * 8;
        float4 v0 = *reinterpret_cast<const float4*>(X + i);
        float4 v1 = *reinterpret_cast<const float4*>(X + i + 4);
        shortx8 s;
        s[0] = f2bf(v0.x); s[1] = f2bf(v0.y); s[2] = f2bf(v0.z); s[3] = f2bf(v0.w);
        s[4] = f2bf(v1.x); s[5] = f2bf(v1.y); s[6] = f2bf(v1.z); s[7] = f2bf(v1.w);
        *reinterpret_cast<shortx8*>(Xb + i) = s;
    } else if (id < 4864) {
        __shared__ float tl[64][65];
        const int wid = id - 4096;
        const int z = wid >> 8, t16 = wid & 255;
        const float* src = (z == 0) ? Wq : (z == 1) ? Wk : Wv;
        short* dst = Wt + (size_t)z * 1024 * 1024;
        const int k0 = (t16 >> 4) * 64, n0 = (t16 & 15) * 64;
        for (int i = t; i < 64 * 64; i += 256) {
            int r = i >> 6, c = i & 63;
            tl[r][c] = src[(size_t)(k0 + r) * 1024 + n0 + c];
        }
        __syncthreads();
        for (int i = t; i < 64 * 64; i += 256) {
            int r = i >> 6, c = i & 63;
            dst[(size_t)(n0 + r) * 1024 + k0 + c] = f2bf(tl[c][r]);
        }
    } else {
        const int z = id - 4864;
        const float* bsrc = (z == 0) ? bq : (z == 1) ? bk : bv;
        for (int i = t; i < 1024; i += 256) bcat[z * 1024 + i] = bsrc[i];
    }
}

// --------------------------------------------------------------------------
// V part of QKV: Vt[b][1024(d)][2048(s)] = (Xb @ Wt[2048:3072]^T + bias)^T.
// 128^2 2-phase loop, grid (64, 8) = 512 blocks.
// --------------------------------------------------------------------------
__global__ __launch_bounds__(256) void qkv_v_kernel(
    const short* __restrict__ Xb, const short* __restrict__ Wt,
    const float* __restrict__ bcat, short* __restrict__ Vt)
{
    __shared__ short as_[128 * 64];
    __shared__ short bs_[128 * 64];
    const int t = threadIdx.x, w = t >> 6, l = t & 63;
    const int m0 = blockIdx.x * 128;
    const int n0 = 2048 + blockIdx.y * 128;
    const int wr = w >> 1, wc = w & 1, lrow = l & 15, quad = l >> 4;

    floatx4 acc[4][4];
    for (int i = 0; i < 4; ++i)
        for (int j = 0; j < 4; ++j) acc[i][j] = floatx4{0.f, 0.f, 0.f, 0.f};

    gemm_loop(Xb + (size_t)m0 * 1024, Wt + (size_t)n0 * 1024,
              1024, 1024, 1024, as_, bs_, acc, w, l);

    for (int i = 0; i < 4; ++i) {
        int rbase = m0 + wr * 64 + i * 16 + quad * 4;
        int b = rbase >> 11, sl = rbase & 2047;
        for (int j = 0; j < 4; ++j) {
            int coln = n0 + wc * 64 + j * 16 + lrow;   // 2048..3071
            int col = coln & 1023;
            float bvv = bcat[coln];
            shortx4 s;
            for (int r = 0; r < 4; ++r) s[r] = f2bf(acc[i][j][r] + bvv);
            *reinterpret_cast<shortx4*>(
                &Vt[((size_t)b * 1024 + col) * 2048 + sl]) = s;
        }
    }
}

// --------------------------------------------------------------------------
// QK part of QKV: C[8192][2048] = Xb @ Wt[0:2048]^T + bcat.  sec = n0>>10:
//   0 -> dQ bf16 [8192][1024], 1 -> dK.
// Grid (32, 8) = exactly 256 blocks. R15: gemm256_loop4 mainloop.
// --------------------------------------------------------------------------
__global__ __launch_bounds__(512, 2) void qkv_qk_kernel(
    const short* __restrict__ Xb, const short* __restrict__ Wt,
    const float* __restrict__ bcat, short* __restrict__ dQ,
    short* __restrict__ dK)
{
    __shared__ short sA[2 * 16384];
    __shared__ short sB[2 * 16384];
    const int t = threadIdx.x;
    const int m0 = blockIdx.x * 256, n0 = blockIdx.y * 256;
    const int w = t >> 6, l = t & 63;
    const int wm = w >> 2, wn = w & 3, lrow = l & 15, quad = l >> 4;
    const int sec = n0 >> 10;

    floatx4 acc[8][4];
#pragma unroll
    for (int i = 0; i < 8; ++i)
#pragma unroll
        for (int j = 0; j < 4; ++j) acc[i][j] = floatx4{0.f, 0.f, 0.f, 0.f};

    gemm256_loop4(Xb + (size_t)m0 * 1024, Wt + (size_t)n0 * 1024,
                  1024, 1024, 1024, sA, sB, acc, t);

    short* outN = (sec == 0) ? dQ : dK;
#pragma unroll
    for (int i = 0; i < 8; ++i) {
        int rbase = m0 + wm * 128 + i * 16 + quad * 4;
#pragma unroll
        for (int j = 0; j < 4; ++j) {
            int coln = n0 + wn * 64 + j * 16 + lrow;   // 0..2047
            int col = coln & 1023;
            float bvv = bcat[coln];
#pragma unroll
            for (int r = 0; r < 4; ++r)
                outN[(size_t)(rbase + r) * 1024 + col] =
                    f2bf(acc[i][j][r] + bvv);
        }
    }
}

// --------------------------------------------------------------------------
// P[m][key] = exp(q.k/32 - 20) bf16 (unnormalized); per-(row, key-tile)
// partial sums -> partials[row*8 + ytile] (no atomics: wn-waves combine via
// disjoint LDS [256][4] slots reusing sA after the final mainloop barrier).
// Grid (rows/256, 8). Full-chunk (gridDim.x==32): bijective XCD remap --
// id%8 (the XCD) fixes the batch (c>>1): per-XCD dK 4MB + dQ 2MB.
// R15: gemm256_loop4 mainloop.
// --------------------------------------------------------------------------
__global__ __launch_bounds__(512, 2) void scores_kernel(
    const short* __restrict__ dQ, const short* __restrict__ dK,
    short* __restrict__ P, float* __restrict__ partials, int row_start)
{
    __shared__ short sA[2 * 16384];
    __shared__ short sB[2 * 16384];
    const int t = threadIdx.x;
    int bx = blockIdx.x, by = blockIdx.y;
    if (gridDim.x == 32) {
        const int c = bx & 7;
        const int k = (bx >> 3) + (by << 2);      // 0..31
        const int bb = c >> 1, half = c & 1;
        bx = bb * 8 + (k & 3) + 4 * half;          // row-tile 0..31
        by = k >> 2;                               // key-tile 0..7
    }
    const int m0 = bx * 256;                  // chunk-local q rows
    const int n0 = by * 256;                  // key tile
    const int g0 = row_start + m0;
    const int b = g0 >> 11;
    const int w = t >> 6, l = t & 63;
    const int wm = w >> 2, wn = w & 3, lrow = l & 15, quad = l >> 4;

    floatx4 acc[8][4];
#pragma unroll
    for (int i = 0; i < 8; ++i)
#pragma unroll
        for (int j = 0; j < 4; ++j) acc[i][j] = floatx4{0.f, 0.f, 0.f, 0.f};

    gemm256_loop4(dQ + (size_t)g0 * 1024, dK + ((size_t)b * 2048 + n0) * 1024,
                  1024, 1024, 1024, sA, sB, acc, t);

    // sred[row_local][wn]: each (row, wn) written exactly once -> no atomics.
    float* sred = reinterpret_cast<float*>(sA);   // 256*4 floats = 4 KiB
#pragma unroll
    for (int i = 0; i < 8; ++i) {
        int rl = wm * 128 + i * 16 + quad * 4;    // block-local row base
        int rloc = m0 + rl;
        float rs[4] = {0.f, 0.f, 0.f, 0.f};
#pragma unroll
        for (int j = 0; j < 4; ++j) {
            int col = n0 + wn * 64 + j * 16 + lrow;
#pragma unroll
            for (int r = 0; r < 4; ++r) {
                short pb = f2bf(__expf(acc[i][j][r] * 0.03125f - 20.0f));
                P[(size_t)(rloc + r) * 2048 + col] = pb;
                rs[r] += bf2f(pb);
            }
        }
#pragma unroll
        for (int r = 0; r < 4; ++r)
            for (int m = 1; m <= 8; m <<= 1)
                rs[r] += __shfl_xor(rs[r], m, 64);
        if (lrow == 0)
#pragma unroll
            for (int r = 0; r < 4; ++r)
                sred[(rl + r) * 4 + wn] = rs[r];
    }
    __syncthreads();
    if (t < 256) {
        float s = sred[t * 4] + sred[t * 4 + 1] + sred[t * 4 + 2] + sred[t * 4 + 3];
        partials[(size_t)(row_start + m0 + t) * 8 + by] = s;
    }
}

// --------------------------------------------------------------------------
// Out[row][d] = (P[m][:] @ V[b][:,d]) / sum_y partials[row][y].
// Vt bf16 [b][d][key]. 128^2 2-phase loop (proven 44.3us), grid (rows/128,
// 8). Full-chunk (gridDim.x==64): bijective XCD remap -- each XCD
// batch-local: Vt working set 16MB -> 4MB.
// --------------------------------------------------------------------------
__global__ __launch_bounds__(256) void pv_kernel(
    const short* __restrict__ P, const short* __restrict__ Vt,
    const float* __restrict__ partials, float* __restrict__ Out, int row_start)
{
    __shared__ short as_[128 * 64];
    __shared__ short bs_[128 * 64];
    const int t = threadIdx.x, w = t >> 6, l = t & 63;
    int bx = blockIdx.x, by = blockIdx.y;
    if (gridDim.x == 64) {
        const int c = bx & 7;
        const int k = (bx >> 3) + (by << 3);      // 0..63
        const int bb = c >> 1, half = c & 1;
        bx = bb * 16 + (k & 7) + 8 * half;         // row-tile 0..63
        by = k >> 3;                               // d-tile 0..7
    }
    const int m0 = bx * 128;                  // chunk-local rows
    const int n0 = by * 128;                  // d tile
    const int g0 = row_start + m0;
    const int b = g0 >> 11;
    const int wr = w >> 1, wc = w & 1, lrow = l & 15, quad = l >> 4;

    floatx4 acc[4][4];
    for (int i = 0; i < 4; ++i)
        for (int j = 0; j < 4; ++j) acc[i][j] = floatx4{0.f, 0.f, 0.f, 0.f};

    gemm_loop(P + (size_t)m0 * 2048, Vt + ((size_t)b * 1024 + n0) * 2048,
              2048, 2048, 2048, as_, bs_, acc, w, l);

    for (int i = 0; i < 4; ++i) {
        int rloc = m0 + wr * 64 + i * 16 + quad * 4;
        int rglb = row_start + rloc;
        float is[4];
        for (int r = 0; r < 4; ++r) {
            const float4* pp =
                reinterpret_cast<const float4*>(&partials[(size_t)(rglb + r) * 8]);
            float4 p0 = pp[0], p1 = pp[1];
            float s = (p0.x + p0.y) + (p0.z + p0.w) +
                      (p1.x + p1.y) + (p1.z + p1.w);
            is[r] = 1.0f / s;
        }
        for (int j = 0; j < 4; ++j) {
            int col = n0 + wc * 64 + j * 16 + lrow;
            for (int r = 0; r < 4; ++r)
                Out[(size_t)(rglb + r) * 1024 + col] = acc[i][j][r] * is[r];
        }
    }
}

// --------------------------------------------------------------------------
extern "C" void kernel_launch(void* const* d_in, const int* in_sizes, int n_in,
                              void* d_out, int out_size, void* d_ws, size_t ws_size,
                              hipStream_t stream)
{
    const float* x  = (const float*)d_in[0];
    const float* Wq = (const float*)d_in[1];
    const float* bq = (const float*)d_in[2];
    const float* Wk = (const float*)d_in[3];
    const float* bk = (const float*)d_in[4];
    const float* Wv = (const float*)d_in[5];
    const float* bv = (const float*)d_in[6];
    float* out = (float*)d_out;

    // d_out doubles as Q/K scratch (exactly 32 MiB): safe by stream ordering.
    short* dQ = (short*)d_out;
    short* dK = dQ + (size_t)8192 * 1024;

    char* ws = (char*)d_ws;
    short* Wt   = (short*)ws;                                 // 6 MiB
    float* bcat = (float*)(ws + 6291456);                     // 12 KiB
    float* partials = (float*)(ws + 6291456 + 12288);         // 256 KiB [8192][8]
    short* Vt   = (short*)(ws + 6291456 + 12288 + 262144);    // 16 MiB
    char*  region = ws + 6291456 + 12288 + 262144 + 16777216; // P / Xb
    const size_t base = 6291456 + 12288 + 262144 + 16777216;  // ~22.3 MiB

    size_t avail = ws_size > base ? ws_size - base : 0;
    long rows_fit = (long)(avail / 4096);   // P row = 2048 bf16 = 4 KiB
    int chunk = (int)(rows_fit & ~255L);    // scores tiles are 256 rows
    if (chunk > 8192) chunk = 8192;
    if (chunk < 256) chunk = 256;           // needs ws >= ~23.3 MiB
    short* Xb = (short*)region;             // 16 MiB, dead before P is written
    short* P  = (short*)region;

    prep_kernel<<<dim3(4867), 256, 0, stream>>>(x, Wq, Wk, Wv, bq, bk, bv,
                                                Xb, Wt, bcat);
    qkv_v_kernel<<<dim3(64, 8), 256, 0, stream>>>(Xb, Wt, bcat, Vt);
    qkv_qk_kernel<<<dim3(32, 8), 512, 0, stream>>>(Xb, Wt, bcat, dQ, dK);

    for (int rs = 0; rs < 8192; rs += chunk) {
        int rows = 8192 - rs;
        if (rows > chunk) rows = chunk;
        scores_kernel<<<dim3(rows / 256, 8), 512, 0, stream>>>(dQ, dK, P, partials, rs);
        pv_kernel<<<dim3(rows / 128, 8), 256, 0, stream>>>(P, Vt, partials, out, rs);
    }
}